// Round 11
// baseline (415.995 us; speedup 1.0000x reference)
//
#include <hip/hip_runtime.h>
#include <hip/hip_bf16.h>
#include <math.h>

// Problem constants
#define BB 4
#define LL 1024
#define DD 1024
#define HH 16
#define DHH 64
#define FFF 4096
#define MM (BB*LL)     // 4096 rows
#define LDQ 3072       // fused QKV row stride

typedef __attribute__((ext_vector_type(8))) short short8;
typedef __attribute__((ext_vector_type(4))) float f32x4;

__device__ __forceinline__ ushort f2bf(float f) {
    __hip_bfloat16 h = __float2bfloat16(f);
    return *(ushort*)&h;
}
__device__ __forceinline__ float bf2f(ushort u) {
    __hip_bfloat16 h = *(__hip_bfloat16*)&u;
    return __bfloat162float(h);
}
__device__ __forceinline__ float fexp2(float x) {
#if __has_builtin(__builtin_amdgcn_exp2f)
    return __builtin_amdgcn_exp2f(x);
#else
    return exp2f(x);
#endif
}

// ---------------- block reduction helper ----------------
__device__ __forceinline__ float block_reduce_sum(float v, float* red, int tid) {
    red[tid] = v;
    __syncthreads();
    for (int off = 128; off > 0; off >>= 1) {
        if (tid < off) red[tid] += red[tid + off];
        __syncthreads();
    }
    float r = red[0];
    __syncthreads();
    return r;
}

// ---------------- elementwise cast fp32 -> bf16 ----------------
__global__ __launch_bounds__(256)
void cast_bf16(const float* __restrict__ in, ushort* __restrict__ out) {
    const int i = blockIdx.x * 256 + threadIdx.x;
    float4 v = ((const float4*)in)[i];
    ushort4 o;
    o.x = f2bf(v.x); o.y = f2bf(v.y); o.z = f2bf(v.z); o.w = f2bf(v.w);
    ((ushort4*)out)[i] = o;
}

// ---------------- bias pre-swizzle: fp32 [row][k] -> bf16 [row][kt][c*4+j] --
__global__ __launch_bounds__(256)
void swizzle_bias(const float* __restrict__ bias, ushort* __restrict__ B) {
    __shared__ float rowbuf[1024];
    const int row = blockIdx.x;
    const int t = threadIdx.x;
    *(float4*)&rowbuf[t * 4] = *(const float4*)&bias[(size_t)row * 1024 + t * 4];
    __syncthreads();
    const int kt = t >> 4, c = t & 15;
    const float s = 1.4426950408889634f;
    ushort4 o;
    o.x = f2bf(rowbuf[kt * 64 + 0 * 16 + c] * s);
    o.y = f2bf(rowbuf[kt * 64 + 1 * 16 + c] * s);
    o.z = f2bf(rowbuf[kt * 64 + 2 * 16 + c] * s);
    o.w = f2bf(rowbuf[kt * 64 + 3 * 16 + c] * s);
    *(ushort4*)&B[(size_t)row * 1024 + t * 4] = o;
}

// ---------------- tiled transpose + cast: W[K][N] fp32 -> WT[N][K] bf16 ----
__global__ __launch_bounds__(256)
void transpose_cast(const float* __restrict__ W, ushort* __restrict__ WT,
                    int K, int N) {
    __shared__ float tile[32][33];
    const int n0 = blockIdx.x * 32, k0 = blockIdx.y * 32;
    const int t = threadIdx.x;
    const int r = t >> 3, c4 = (t & 7) * 4;
    float4 v = *(const float4*)&W[(size_t)(k0 + r) * N + n0 + c4];
    tile[r][c4 + 0] = v.x; tile[r][c4 + 1] = v.y;
    tile[r][c4 + 2] = v.z; tile[r][c4 + 3] = v.w;
    __syncthreads();
    ushort4 o;
    o.x = f2bf(tile[c4 + 0][r]);
    o.y = f2bf(tile[c4 + 1][r]);
    o.z = f2bf(tile[c4 + 2][r]);
    o.w = f2bf(tile[c4 + 3][r]);
    *(ushort4*)&WT[(size_t)(n0 + r) * K + k0 + c4] = o;
}

// ---------------- bf16 V-transpose: QKVb V-cols -> Vt[b, hd][k] ------------
// Vt[(b*1024 + j)*1024 + k] = QKVb[(b*1024 + k)*3072 + 2048 + j]
__global__ __launch_bounds__(256)
void transpose_v(const ushort* __restrict__ QKVb, ushort* __restrict__ Vt) {
    __shared__ ushort tile[32][36];
    const int j0 = blockIdx.x * 32, k0 = blockIdx.y * 32, b = blockIdx.z;
    const int t = threadIdx.x;
    const int r = t >> 3, c4 = (t & 7) * 4;
    ushort4 v = *(const ushort4*)&QKVb[((size_t)(b * 1024 + k0 + r)) * LDQ + 2048 + j0 + c4];
    tile[r][c4 + 0] = v.x; tile[r][c4 + 1] = v.y;
    tile[r][c4 + 2] = v.z; tile[r][c4 + 3] = v.w;
    __syncthreads();
    ushort4 o;
    o.x = tile[c4 + 0][r];
    o.y = tile[c4 + 1][r];
    o.z = tile[c4 + 2][r];
    o.w = tile[c4 + 3][r];
    *(ushort4*)&Vt[((size_t)(b * 1024 + j0 + r)) * 1024 + k0 + c4] = o;
}

// ---------------- concat 3 bias vectors of 1024 ----------------
__global__ __launch_bounds__(256)
void concat3(const float* __restrict__ a, const float* __restrict__ b,
             const float* __restrict__ c, float* __restrict__ o) {
    const int i = blockIdx.x * 256 + threadIdx.x;
    o[i] = (i < 1024) ? a[i] : ((i < 2048) ? b[i - 1024] : c[i - 2048]);
}

// ---------------- bf16 MFMA GEMM, m97 structure (BK=32) + XCD swizzle ------
// C[M,N] = A[M,K] @ Bt[N,K]^T + bias. 128x128 tile, 16 KB LDS, 3 blk/CU.
// relu / obf16 / qlim (cols<qlim scaled 0.125)
__global__ __launch_bounds__(256)
void gemm_bf16(const ushort* __restrict__ A, const ushort* __restrict__ Bt,
               const float* __restrict__ bias, void* __restrict__ C,
               int M, int N, int K, int relu, int obf16, int qlim) {
    __shared__ ushort Als[128 * 32];
    __shared__ ushort Bls[128 * 32];

    const int L = blockIdx.x + gridDim.x * blockIdx.y;
    const int xcd = L & 7;
    const int idx = L >> 3;
    const int mpx = gridDim.y >> 3;
    const int bm = (xcd * mpx + (idx % mpx)) * 128;
    const int bn = (idx / mpx) * 128;

    const int t = threadIdx.x;
    const int lane = t & 63;
    const int w = t >> 6;
    const int wm = (w >> 1) * 64;
    const int wn = (w & 1) * 64;
    const int fm = lane & 15;
    const int kg = lane >> 4;

    f32x4 acc[4][4] = {};

    for (int k0 = 0; k0 < K; k0 += 32) {
        #pragma unroll
        for (int j = 0; j < 2; ++j) {
            const int chunk = j * 256 + t;
            const int row = chunk >> 2, kc = chunk & 3;
            const ushort* ga = A + (size_t)(bm + row) * K + k0 + kc * 8;
            __builtin_amdgcn_global_load_lds(
                (const __attribute__((address_space(1))) void*)ga,
                (__attribute__((address_space(3))) void*)(Als + chunk * 8), 16, 0, 0);
            const ushort* gb = Bt + (size_t)(bn + row) * K + k0 + kc * 8;
            __builtin_amdgcn_global_load_lds(
                (const __attribute__((address_space(1))) void*)gb,
                (__attribute__((address_space(3))) void*)(Bls + chunk * 8), 16, 0, 0);
        }
        __syncthreads();

        short8 af[4], bfr[4];
        #pragma unroll
        for (int i = 0; i < 4; ++i)
            af[i] = *(const short8*)&Als[(wm + i * 16 + fm) * 32 + kg * 8];
        #pragma unroll
        for (int j = 0; j < 4; ++j)
            bfr[j] = *(const short8*)&Bls[(wn + j * 16 + fm) * 32 + kg * 8];
        #pragma unroll
        for (int i = 0; i < 4; ++i)
            #pragma unroll
            for (int j = 0; j < 4; ++j)
                acc[i][j] = __builtin_amdgcn_mfma_f32_16x16x32_bf16(
                    af[i], bfr[j], acc[i][j], 0, 0, 0);
        __syncthreads();
    }

    const int orow0 = (lane >> 4) * 4;
    const int ocol = lane & 15;
    #pragma unroll
    for (int j = 0; j < 4; ++j) {
        const int n = bn + wn + j * 16 + ocol;
        const float bv = bias[n];
        #pragma unroll
        for (int i = 0; i < 4; ++i) {
            const int m0 = bm + wm + i * 16 + orow0;
            #pragma unroll
            for (int r = 0; r < 4; ++r) {
                const int m = m0 + r;
                float v = acc[i][j][r] + bv;
                if (relu) v = fmaxf(v, 0.0f);
                if (n < qlim) v *= 0.125f;
                if (obf16)
                    ((ushort*)C)[(size_t)m * N + n] = f2bf(v);
                else
                    ((float*)C)[(size_t)m * N + n] = v;
            }
        }
    }
}

// ---------------- split-K bf16 MFMA GEMM (BN=64, BK=64), fp32 partials -----
__global__ __launch_bounds__(256)
void gemm_bf16_sk(const ushort* __restrict__ A, const ushort* __restrict__ Bt,
                  float* __restrict__ P, int M, int N, int K) {
    __shared__ ushort Als0[128 * 32];
    __shared__ ushort Als1[128 * 32];
    __shared__ ushort Bls0[64 * 32];
    __shared__ ushort Bls1[64 * 32];

    const int L = blockIdx.x + gridDim.x * blockIdx.y;
    const int xcd = L & 7;
    const int idx = L >> 3;
    const int mpx = gridDim.y >> 3;
    const int bm = (xcd * mpx + (idx % mpx)) * 128;
    const int bn = (idx / mpx) * 64;
    const int kbeg = blockIdx.z * (K >> 1);
    const int kend = kbeg + (K >> 1);

    const int t = threadIdx.x;
    const int lane = t & 63;
    const int w = t >> 6;
    const int wm = (w >> 1) * 64;
    const int wn = (w & 1) * 32;
    const int fm = lane & 15;
    const int kg = lane >> 4;

    f32x4 acc[4][2] = {};

    for (int k0 = kbeg; k0 < kend; k0 += 64) {
        #pragma unroll
        for (int j = 0; j < 2; ++j) {
            const int chunk = j * 256 + t;
            const int row = chunk >> 2, kc = chunk & 3;
            const ushort* ga0 = A + (size_t)(bm + row) * K + k0 + kc * 8;
            __builtin_amdgcn_global_load_lds(
                (const __attribute__((address_space(1))) void*)ga0,
                (__attribute__((address_space(3))) void*)(Als0 + chunk * 8), 16, 0, 0);
            const ushort* ga1 = ga0 + 32;
            __builtin_amdgcn_global_load_lds(
                (const __attribute__((address_space(1))) void*)ga1,
                (__attribute__((address_space(3))) void*)(Als1 + chunk * 8), 16, 0, 0);
        }
        {
            const int chunk = t;
            const int row = chunk >> 2, kc = chunk & 3;
            const ushort* gb0 = Bt + (size_t)(bn + row) * K + k0 + kc * 8;
            __builtin_amdgcn_global_load_lds(
                (const __attribute__((address_space(1))) void*)gb0,
                (__attribute__((address_space(3))) void*)(Bls0 + chunk * 8), 16, 0, 0);
            const ushort* gb1 = gb0 + 32;
            __builtin_amdgcn_global_load_lds(
                (const __attribute__((address_space(1))) void*)gb1,
                (__attribute__((address_space(3))) void*)(Bls1 + chunk * 8), 16, 0, 0);
        }
        __syncthreads();

        short8 af[4][2], bfr[2][2];
        #pragma unroll
        for (int i = 0; i < 4; ++i) {
            af[i][0] = *(const short8*)&Als0[(wm + i * 16 + fm) * 32 + kg * 8];
            af[i][1] = *(const short8*)&Als1[(wm + i * 16 + fm) * 32 + kg * 8];
        }
        #pragma unroll
        for (int j = 0; j < 2; ++j) {
            bfr[j][0] = *(const short8*)&Bls0[(wn + j * 16 + fm) * 32 + kg * 8];
            bfr[j][1] = *(const short8*)&Bls1[(wn + j * 16 + fm) * 32 + kg * 8];
        }
        #pragma unroll
        for (int i = 0; i < 4; ++i)
            #pragma unroll
            for (int j = 0; j < 2; ++j) {
                acc[i][j] = __builtin_amdgcn_mfma_f32_16x16x32_bf16(
                    af[i][0], bfr[j][0], acc[i][j], 0, 0, 0);
                acc[i][j] = __builtin_amdgcn_mfma_f32_16x16x32_bf16(
                    af[i][1], bfr[j][1], acc[i][j], 0, 0, 0);
            }
        __syncthreads();
    }

    float* Pz = P + (size_t)blockIdx.z * M * N;
    const int orow0 = (lane >> 4) * 4;
    const int ocol = lane & 15;
    #pragma unroll
    for (int j = 0; j < 2; ++j) {
        const int n = bn + wn + j * 16 + ocol;
        #pragma unroll
        for (int i = 0; i < 4; ++i) {
            const int m0 = bm + wm + i * 16 + orow0;
            #pragma unroll
            for (int r = 0; r < 4; ++r)
                Pz[(size_t)(m0 + r) * N + n] = acc[i][j][r];
        }
    }
}

// ---------------- MFMA flash attention, lean softmax ----------------
__global__ __launch_bounds__(256, 3)
void attn_mfma(const ushort* __restrict__ QKVb, const ushort* __restrict__ Vt,
               const ushort* __restrict__ biasw, const int* __restrict__ mask,
               ushort* __restrict__ ctx) {
    const int q0 = blockIdx.x * 64;
    const int h = blockIdx.y;
    const int b = blockIdx.z;
    const int t = threadIdx.x;
    const int lane = t & 63;
    const int w = t >> 6;
    const int g = lane >> 4;
    const int c = lane & 15;

    __shared__ ushort QP[64 * 72];
    __shared__ ushort Ks[64 * 72];
    __shared__ ushort Vs[64 * 72];
    __shared__ int maskS[LL];

    #pragma unroll
    for (int i = 0; i < 2; ++i) {
        const int chunk = i * 256 + t;
        const int row = chunk >> 3, c8 = (chunk & 7) * 8;
        *(short8*)&QP[row * 72 + c8] =
            *(const short8*)(QKVb + ((size_t)(b * LL + q0 + row)) * LDQ + h * DHH + c8);
    }
    ((int4*)maskS)[t] = ((const int4*)(mask + b * LL))[t];

    short8 pk[2], pv[2];
    #pragma unroll
    for (int i = 0; i < 2; ++i) {
        const int chunk = i * 256 + t;
        const int row = chunk >> 3, c8 = (chunk & 7) * 8;
        pk[i] = *(const short8*)(QKVb + ((size_t)(b * LL + row)) * LDQ + 1024 + h * DHH + c8);
        pv[i] = *(const short8*)(Vt + ((size_t)((b * HH + h) * DHH + row)) * LL + c8);
    }
    __syncthreads();

    short8 aq0 = *(const short8*)&QP[(w * 16 + c) * 72 + g * 8];
    short8 aq1 = *(const short8*)&QP[(w * 16 + c) * 72 + g * 8 + 32];
    ushort* Pw = QP + w * (16 * 72);

    float m_pr[4] = {-3.4e38f, -3.4e38f, -3.4e38f, -3.4e38f};
    float l_run[4] = {0.f, 0.f, 0.f, 0.f};
    f32x4 acc_o[4] = {};

    for (int kt = 0; kt < 16; ++kt) {
        #pragma unroll
        for (int i = 0; i < 2; ++i) {
            const int chunk = i * 256 + t;
            const int row = chunk >> 3, c8 = (chunk & 7) * 8;
            *(short8*)&Ks[row * 72 + c8] = pk[i];
            *(short8*)&Vs[row * 72 + c8] = pv[i];
        }
        __syncthreads();

        if (kt < 15) {
            const int k0n = (kt + 1) * 64;
            #pragma unroll
            for (int i = 0; i < 2; ++i) {
                const int chunk = i * 256 + t;
                const int row = chunk >> 3, c8 = (chunk & 7) * 8;
                pk[i] = *(const short8*)(QKVb + ((size_t)(b * LL + k0n + row)) * LDQ + 1024 + h * DHH + c8);
                pv[i] = *(const short8*)(Vt + ((size_t)((b * HH + h) * DHH + row)) * LL + k0n + c8);
            }
        }

        ushort4 pb[4];
        #pragma unroll
        for (int r = 0; r < 4; ++r) {
            const int q = q0 + w * 16 + 4 * g + r;
            pb[r] = *(const ushort4*)&biasw[((size_t)(b * LL + q) * 16 + kt) * 64 + c * 4];
        }
        int mk[4];
        #pragma unroll
        for (int j = 0; j < 4; ++j) mk[j] = maskS[kt * 64 + j * 16 + c];

        f32x4 accs[4] = {};
        #pragma unroll
        for (int j = 0; j < 4; ++j) {
            short8 bk0 = *(const short8*)&Ks[(j * 16 + c) * 72 + g * 8];
            short8 bk1 = *(const short8*)&Ks[(j * 16 + c) * 72 + g * 8 + 32];
            accs[j] = __builtin_amdgcn_mfma_f32_16x16x32_bf16(aq0, bk0, accs[j], 0, 0, 0);
            accs[j] = __builtin_amdgcn_mfma_f32_16x16x32_bf16(aq1, bk1, accs[j], 0, 0, 0);
        }

        float sc[4][4];
        #pragma unroll
        for (int j = 0; j < 4; ++j)
            #pragma unroll
            for (int r = 0; r < 4; ++r) {
                const float bw = bf2f(((const ushort*)&pb[r])[j]);
                const float v = accs[j][r] * bw;
                sc[j][r] = (mk[j] == 0) ? -14427.0f : v;
            }

        float mt[4];
        #pragma unroll
        for (int r = 0; r < 4; ++r)
            mt[r] = fmaxf(fmaxf(sc[0][r], sc[1][r]), fmaxf(sc[2][r], sc[3][r]));
        #pragma unroll
        for (int d = 1; d < 16; d <<= 1)
            #pragma unroll
            for (int r = 0; r < 4; ++r)
                mt[r] = fmaxf(mt[r], __shfl_xor(mt[r], d));

        float al[4], lt[4];
        #pragma unroll
        for (int r = 0; r < 4; ++r) {
            const float mn = fmaxf(m_pr[r], mt[r]);
            al[r] = fexp2(m_pr[r] - mn);
            m_pr[r] = mn;
            lt[r] = 0.0f;
        }

        #pragma unroll
        for (int j = 0; j < 4; ++j)
            #pragma unroll
            for (int r = 0; r < 4; ++r) {
                const float pe = fexp2(sc[j][r] - m_pr[r]);
                lt[r] += pe;
                Pw[(4 * g + r) * 72 + j * 16 + c] = f2bf(pe);
            }

        const bool ones = (al[0] == 1.0f) & (al[1] == 1.0f) &
                          (al[2] == 1.0f) & (al[3] == 1.0f);
        if (!__all(ones)) {
            #pragma unroll
            for (int r = 0; r < 4; ++r) l_run[r] *= al[r];
            #pragma unroll
            for (int j = 0; j < 4; ++j)
                #pragma unroll
                for (int r = 0; r < 4; ++r)
                    acc_o[j][r] *= al[r];
        }
        #pragma unroll
        for (int r = 0; r < 4; ++r) l_run[r] += lt[r];

        #pragma unroll
        for (int ks = 0; ks < 2; ++ks) {
            short8 ap = *(const short8*)&Pw[c * 72 + ks * 32 + g * 8];
            #pragma unroll
            for (int j = 0; j < 4; ++j) {
                short8 bv8 = *(const short8*)&Vs[(j * 16 + c) * 72 + ks * 32 + g * 8];
                acc_o[j] = __builtin_amdgcn_mfma_f32_16x16x32_bf16(ap, bv8, acc_o[j], 0, 0, 0);
            }
        }
        __syncthreads();
    }

    #pragma unroll
    for (int r = 0; r < 4; ++r) {
        float l = l_run[r];
        #pragma unroll
        for (int d = 1; d < 16; d <<= 1) l += __shfl_xor(l, d);
        const float inv = 1.0f / l;
        #pragma unroll
        for (int j = 0; j < 4; ++j)
            ctx[((size_t)(b * LL + q0 + w * 16 + 4 * g + r)) * DD + h * DHH + j * 16 + c] =
                f2bf(acc_o[j][r] * inv);
    }
}

// ---------------- split-K reduce + col-bias + residual + LayerNorm ---------
__global__ __launch_bounds__(256)
void add_ln_kernel(const float* __restrict__ P0, const float* __restrict__ P1,
                   const float* __restrict__ cb, const float* __restrict__ bres,
                   const float* __restrict__ gamma, const float* __restrict__ beta,
                   float* __restrict__ out, ushort* __restrict__ outb) {
    const int row = blockIdx.x;
    const int tid = threadIdx.x;
    __shared__ float red[256];

    const size_t base = (size_t)row * DD;
    float v[4];
    float sum = 0.0f;
    #pragma unroll
    for (int i = 0; i < 4; ++i) {
        const int col = tid + i * 256;
        v[i] = P0[base + col] + P1[base + col] + cb[col] + bres[base + col];
        sum += v[i];
    }
    const float mean = block_reduce_sum(sum, red, tid) * (1.0f / 1024.0f);
    float vs = 0.0f;
    #pragma unroll
    for (int i = 0; i < 4; ++i) {
        const float dlt = v[i] - mean;
        vs += dlt * dlt;
    }
    const float var = block_reduce_sum(vs, red, tid) * (1.0f / 1024.0f);
    const float rstd = rsqrtf(var + 1e-12f);
    #pragma unroll
    for (int i = 0; i < 4; ++i) {
        const int col = tid + i * 256;
        const float o = gamma[col] * (v[i] - mean) * rstd + beta[col];
        out[base + col] = o;
        if (outb) outb[base + col] = f2bf(o);
    }
}

extern "C" void kernel_launch(void* const* d_in, const int* in_sizes, int n_in,
                              void* d_out, int out_size, void* d_ws, size_t ws_size,
                              hipStream_t stream) {
    const float* x         = (const float*)d_in[0];
    const float* attn_bias = (const float*)d_in[1];
    const int*   src_mask  = (const int*)  d_in[2];
    const float* wq = (const float*)d_in[3];
    const float* bq = (const float*)d_in[4];
    const float* wk = (const float*)d_in[5];
    const float* bk = (const float*)d_in[6];
    const float* wv = (const float*)d_in[7];
    const float* bv = (const float*)d_in[8];
    const float* wo = (const float*)d_in[9];
    const float* bo = (const float*)d_in[10];
    const float* gamma1 = (const float*)d_in[11];
    const float* beta1  = (const float*)d_in[12];
    const float* w1 = (const float*)d_in[13];
    const float* b1 = (const float*)d_in[14];
    const float* w2 = (const float*)d_in[15];
    const float* b2 = (const float*)d_in[16];
    const float* gamma2 = (const float*)d_in[17];
    const float* beta2  = (const float*)d_in[18];
    float* out = (float*)d_out;

    const size_t MB = 1024 * 1024;
    char* W = (char*)d_ws;
    ushort* xb    = (ushort*)(W + 0);
    ushort* ctxb  = (ushort*)(W + 0);
    ushort* W1T   = (ushort*)(W + 0);
    ushort* QKVb  = (ushort*)(W + 8 * MB);
    float*  Hb    = (float*) (W + 8 * MB);
    ushort* Hbb   = (ushort*)(W + 24 * MB);
    ushort* W2T   = (ushort*)(W + 24 * MB);
    ushort* F1b   = (ushort*)(W + 32 * MB);
    ushort* Vt    = (ushort*)(W + 40 * MB);
    ushort* WQKVT = (ushort*)(W + 48 * MB);
    ushort* WOT   = (ushort*)(W + 48 * MB);
    float*  bqkv  = (float*) (W + 62 * MB);
    ushort* biasw = (ushort*)(W + 64 * MB);
    float*  P0    = (float*) (W + 64 * MB);   // P1 = P0 + MM*DD

    dim3 blk(256);

    // 1. cast x -> bf16; pre-swizzle attn_bias
    cast_bf16<<<dim3(4096), blk, 0, stream>>>(x, xb);
    swizzle_bias<<<dim3(4096), blk, 0, stream>>>(attn_bias, biasw);
    // 2. QKV weight transposes + bias concat
    transpose_cast<<<dim3(32, 32), blk, 0, stream>>>(wq, WQKVT, DD, DD);
    transpose_cast<<<dim3(32, 32), blk, 0, stream>>>(wk, WQKVT + 1024 * 1024, DD, DD);
    transpose_cast<<<dim3(32, 32), blk, 0, stream>>>(wv, WQKVT + 2048 * 1024, DD, DD);
    concat3<<<dim3(12), blk, 0, stream>>>(bq, bk, bv, bqkv);
    // 3. fused QKV projection (bf16 out; Q cols scaled 0.125)
    gemm_bf16<<<dim3(24, 32), blk, 0, stream>>>(xb, WQKVT, bqkv, QKVb,
                                                MM, LDQ, DD, 0, 1, 1024);
    // 3b. V -> Vt coalesced transpose
    transpose_v<<<dim3(32, 32, BB), blk, 0, stream>>>(QKVb, Vt);
    // 4. MFMA flash attention -> ctx bf16
    attn_mfma<<<dim3(16, HH, BB), blk, 0, stream>>>(QKVb, Vt, biasw, src_mask, ctxb);
    // 5. WO transpose + split-K output projection -> P0/P1
    transpose_cast<<<dim3(32, 32), blk, 0, stream>>>(wo, WOT, DD, DD);
    gemm_bf16_sk<<<dim3(16, 32, 2), blk, 0, stream>>>(ctxb, WOT, P0, MM, DD, DD);
    // 6. W1 transpose into dead ctxb region
    transpose_cast<<<dim3(128, 32), blk, 0, stream>>>(w1, W1T, DD, FFF);
    // 7. h = LN(P0+P1+bo + x), fp32 + bf16
    add_ln_kernel<<<dim3(MM), blk, 0, stream>>>(P0, P0 + (size_t)MM * DD, bo, x,
                                                gamma1, beta1, Hb, Hbb);
    // 8. FFN1 (relu, bf16 out)
    gemm_bf16<<<dim3(32, 32), blk, 0, stream>>>(Hbb, W1T, b1, F1b,
                                                MM, FFF, DD, 1, 1, 0);
    // 9. W2 transpose into dead Hbb region; split-K FFN2 -> P0/P1
    transpose_cast<<<dim3(32, 128), blk, 0, stream>>>(w2, W2T, FFF, DD);
    gemm_bf16_sk<<<dim3(16, 32, 2), blk, 0, stream>>>(F1b, W2T, P0, MM, DD, FFF);
    // 10. out = LN(P0+P1+b2 + h)
    add_ln_kernel<<<dim3(MM), blk, 0, stream>>>(P0, P0 + (size_t)MM * DD, b2, Hb,
                                                gamma2, beta2, out, nullptr);
}